// Round 6
// baseline (119.523 us; speedup 1.0000x reference)
//
#include <hip/hip_runtime.h>

#define LOG2E 1.4426950408889634f

constexpr int Bsz = 4096, Ssz = 128, Isz = 64, MOTOR = 32;
constexpr int BT = 4, NT = 256;   // 256 thr = 128 s x 2 j-halves; 4 rows/block

// ---- prep: fold constants, pack T[quad][{a,b,w}][s] as float4 ----
// a = -sigma*log2e ; b = sigma*mu*log2e ; w = w*mask*erev (sign carries erev)
__global__ void ltc_prep(const float* __restrict__ w, const float* __restrict__ sigma,
                         const float* __restrict__ mu, const float* __restrict__ erev,
                         const float* __restrict__ smask,
                         const float* __restrict__ sw, const float* __restrict__ ssig,
                         const float* __restrict__ smu, const float* __restrict__ serev,
                         const float* __restrict__ ssmask,
                         float4* __restrict__ Tm, float4* __restrict__ Ts)
{
  int idx = blockIdx.x * blockDim.x + threadIdx.x;
  if (idx < 32 * Ssz) {                    // main: 32 j-quads x 128 s
    int q = idx >> 7, s = idx & 127;
    float4 a, b, wv;
    #pragma unroll
    for (int jj = 0; jj < 4; ++jj) {
      int e = (q * 4 + jj) * Ssz + s;
      float sg = sigma[e];
      (&a.x)[jj] = -sg * LOG2E;
      (&b.x)[jj] = sg * mu[e] * LOG2E;
      (&wv.x)[jj] = w[e] * smask[e] * erev[e];
    }
    Tm[(q * 3 + 0) * Ssz + s] = a;
    Tm[(q * 3 + 1) * Ssz + s] = b;
    Tm[(q * 3 + 2) * Ssz + s] = wv;
  } else if (idx < 32 * Ssz + 16 * Ssz) {  // sensory: 16 i-quads x 128 s
    int k = idx - 32 * Ssz;
    int q = k >> 7, s = k & 127;
    float4 a, b, wv;
    #pragma unroll
    for (int jj = 0; jj < 4; ++jj) {
      int e = (q * 4 + jj) * Ssz + s;
      float sg = ssig[e];
      (&a.x)[jj] = -sg * LOG2E;
      (&b.x)[jj] = sg * smu[e] * LOG2E;
      (&wv.x)[jj] = sw[e] * ssmask[e] * serev[e];
    }
    Ts[(q * 3 + 0) * Ssz + s] = a;
    Ts[(q * 3 + 1) * Ssz + s] = b;
    Ts[(q * 3 + 2) * Ssz + s] = wv;
  }
}

__launch_bounds__(NT, 8)   // hard-cap 64 VGPR -> 4+ waves/SIMD; live set ~50
__global__ void ltc_main(const float* __restrict__ inputs, const float* __restrict__ states,
                         const float* __restrict__ gleak, const float* __restrict__ vleak,
                         const float* __restrict__ cmv,
                         const float* __restrict__ iw, const float* __restrict__ ib,
                         const float* __restrict__ ow, const float* __restrict__ ob,
                         const float4* __restrict__ Tm, const float4* __restrict__ Ts,
                         float* __restrict__ out)
{
  __shared__ float vsh[BT][Ssz];      // 2 KB
  __shared__ float xsh[BT][Isz];      // 1 KB
  __shared__ float redn[2][2][Ssz];   // 1 KB  [writer-half][row-slot][s]
  __shared__ float redd[2][2][Ssz];   // 1 KB

  const int t = threadIdx.x;
  const int s = t & 127;
  const int h = t >> 7;               // j-half 0/1
  const int b0 = blockIdx.x * BT;

  // stage x = inputs*iw + ib and v = states into LDS
  { int r = t >> 6, i = t & 63;
    xsh[r][i] = inputs[(b0 + r) * Isz + i] * iw[i] + ib[i]; }
  for (int k = t; k < BT * Ssz; k += NT) {
    int r = k >> 7, ss = k & 127;
    vsh[r][ss] = states[(b0 + r) * Ssz + ss];
  }
  const float cmt = cmv[s] * 6.0f;    // cm / (1.0/6)
  const float gl = gleak[s];
  const float gv = gl * vleak[s];
  const float dbase = cmt + gl + 1e-8f;
  __syncthreads();

  // ---- sensory partials over this half's 8 i-quads ----
  float sn[BT] = {0.f, 0.f, 0.f, 0.f}, sd[BT] = {0.f, 0.f, 0.f, 0.f};
  {
    const float4* pb = Ts + (h * 8 * 3 + 1) * Ssz + s;
    #pragma unroll 2
    for (int q = 0; q < 8; ++q) {
      float4 a4 = pb[-Ssz], b4 = pb[0], w4 = pb[Ssz];
      pb += 3 * Ssz;
      int col = (h * 8 + q) * 4;
      #pragma unroll
      for (int r = 0; r < BT; ++r) {
        float4 xq = *(const float4*)&xsh[r][col];   // broadcast read
        #pragma unroll
        for (int jj = 0; jj < 4; ++jj) {
          float arg = fmaf((&a4.x)[jj], (&xq.x)[jj], (&b4.x)[jj]);
          float u = __builtin_amdgcn_exp2f(arg);
          float sig = __builtin_amdgcn_rcpf(1.0f + u);
          sn[r] = fmaf((&w4.x)[jj], sig, sn[r]);
          sd[r] = fmaf(fabsf((&w4.x)[jj]), sig, sd[r]);
        }
      }
    }
  }

  // ---- 6 ODE unfolds ----
  #pragma unroll 1
  for (int it = 0; it < 6; ++it) {
    float num[BT], den[BT];
    #pragma unroll
    for (int r = 0; r < BT; ++r) { num[r] = sn[r]; den[r] = sd[r]; }

    const float4* pb = Tm + (h * 16 * 3 + 1) * Ssz + s;
    #pragma unroll 2
    for (int q = 0; q < 16; ++q) {
      float4 a4 = pb[-Ssz], b4 = pb[0], w4 = pb[Ssz];
      pb += 3 * Ssz;
      int col = (h * 16 + q) * 4;
      #pragma unroll
      for (int r = 0; r < BT; ++r) {
        float4 vq = *(const float4*)&vsh[r][col];   // broadcast read
        #pragma unroll
        for (int jj = 0; jj < 4; ++jj) {
          float arg = fmaf((&a4.x)[jj], (&vq.x)[jj], (&b4.x)[jj]);
          float u = __builtin_amdgcn_exp2f(arg);
          float sig = __builtin_amdgcn_rcpf(1.0f + u);
          num[r] = fmaf((&w4.x)[jj], sig, num[r]);
          den[r] = fmaf(fabsf((&w4.x)[jj]), sig, den[r]);
        }
      }
    }

    // 2-way exchange: write partials for the rows the partner finalizes
    redn[h][0][s] = num[2 - 2 * h]; redn[h][1][s] = num[3 - 2 * h];
    redd[h][0][s] = den[2 - 2 * h]; redd[h][1][s] = den[3 - 2 * h];
    __syncthreads();                 // B1: red visible; all vsh reads done
    #pragma unroll
    for (int k2 = 0; k2 < 2; ++k2) {
      int r = 2 * h + k2;            // rows this half finalizes
      float fn = num[r] + redn[1 - h][k2][s];
      float fd = den[r] + redd[1 - h][k2][s];
      float vo = vsh[r][s];
      vsh[r][s] = (fmaf(cmt, vo, gv) + fn) * __builtin_amdgcn_rcpf(dbase + fd);
    }
    __syncthreads();                 // B2: new v visible; red reusable
  }

  // ---- outputs: [B*32] motor affine, then [B*128] v_pre ----
  for (int k = t; k < BT * Ssz; k += NT) {
    int r = k >> 7, ss = k & 127;
    out[Bsz * MOTOR + (b0 + r) * Ssz + ss] = vsh[r][ss];
  }
  if (t < BT * MOTOR) {
    int r = t >> 5, m = t & 31;
    out[(b0 + r) * MOTOR + m] = fmaf(vsh[r][m], ow[m], ob[m]);
  }
}

extern "C" void kernel_launch(void* const* d_in, const int* in_sizes, int n_in,
                              void* d_out, int out_size, void* d_ws, size_t ws_size,
                              hipStream_t stream) {
  const float* inputs = (const float*)d_in[0];
  const float* states = (const float*)d_in[1];
  const float* gleak  = (const float*)d_in[2];
  const float* vleak  = (const float*)d_in[3];
  const float* cmv    = (const float*)d_in[4];
  const float* w      = (const float*)d_in[5];
  const float* sigma  = (const float*)d_in[6];
  const float* mu     = (const float*)d_in[7];
  const float* erev   = (const float*)d_in[8];
  const float* sw     = (const float*)d_in[9];
  const float* ssig   = (const float*)d_in[10];
  const float* smu    = (const float*)d_in[11];
  const float* serev  = (const float*)d_in[12];
  const float* smask  = (const float*)d_in[13];
  const float* ssmask = (const float*)d_in[14];
  const float* iw     = (const float*)d_in[15];
  const float* ib     = (const float*)d_in[16];
  const float* ow     = (const float*)d_in[17];
  const float* ob     = (const float*)d_in[18];

  char* ws = (char*)d_ws;
  float4* Tm = (float4*)ws;                  // 32 quads * 3 * 128 * 16B = 196608
  float4* Ts = (float4*)(ws + 196608);       // 16 quads * 3 * 128 * 16B =  98304
  float* out = (float*)d_out;

  constexpr int prep_items = 32 * Ssz + 16 * Ssz;   // 6144
  ltc_prep<<<(prep_items + 255) / 256, 256, 0, stream>>>(
      w, sigma, mu, erev, smask, sw, ssig, smu, serev, ssmask, Tm, Ts);
  ltc_main<<<Bsz / BT, NT, 0, stream>>>(
      inputs, states, gleak, vleak, cmv, iw, ib, ow, ob, Tm, Ts, out);
}

// Round 7
// 113.506 us; speedup vs baseline: 1.0530x; 1.0530x over previous
//
#include <hip/hip_runtime.h>

#define LOG2E 1.4426950408889634f

constexpr int Bsz = 4096, Ssz = 128, Isz = 64, MOTOR = 32;
constexpr int BT = 4, NT = 256, R = 2;   // 256 thr = 128 s x 2 row-groups; 2 rows/thread

// ---- prep: fold constants, pack T[quad][{a,b,w}][s] as float4 ----
// a = -sigma*log2e ; b = sigma*mu*log2e ; w = w*mask*erev (sign carries erev)
__global__ void ltc_prep(const float* __restrict__ w, const float* __restrict__ sigma,
                         const float* __restrict__ mu, const float* __restrict__ erev,
                         const float* __restrict__ smask,
                         const float* __restrict__ sw, const float* __restrict__ ssig,
                         const float* __restrict__ smu, const float* __restrict__ serev,
                         const float* __restrict__ ssmask,
                         float4* __restrict__ Tm, float4* __restrict__ Ts)
{
  int idx = blockIdx.x * blockDim.x + threadIdx.x;
  if (idx < 32 * Ssz) {                    // main: 32 j-quads x 128 s
    int q = idx >> 7, s = idx & 127;
    float4 a, b, wv;
    #pragma unroll
    for (int jj = 0; jj < 4; ++jj) {
      int e = (q * 4 + jj) * Ssz + s;
      float sg = sigma[e];
      (&a.x)[jj] = -sg * LOG2E;
      (&b.x)[jj] = sg * mu[e] * LOG2E;
      (&wv.x)[jj] = w[e] * smask[e] * erev[e];
    }
    Tm[(q * 3 + 0) * Ssz + s] = a;
    Tm[(q * 3 + 1) * Ssz + s] = b;
    Tm[(q * 3 + 2) * Ssz + s] = wv;
  } else if (idx < 32 * Ssz + 16 * Ssz) {  // sensory: 16 i-quads x 128 s
    int k = idx - 32 * Ssz;
    int q = k >> 7, s = k & 127;
    float4 a, b, wv;
    #pragma unroll
    for (int jj = 0; jj < 4; ++jj) {
      int e = (q * 4 + jj) * Ssz + s;
      float sg = ssig[e];
      (&a.x)[jj] = -sg * LOG2E;
      (&b.x)[jj] = sg * smu[e] * LOG2E;
      (&wv.x)[jj] = sw[e] * ssmask[e] * serev[e];
    }
    Ts[(q * 3 + 0) * Ssz + s] = a;
    Ts[(q * 3 + 1) * Ssz + s] = b;
    Ts[(q * 3 + 2) * Ssz + s] = wv;
  }
}

__launch_bounds__(NT, 4)   // cap 128 VGPR; expected live ~70-100, no spill
__global__ void ltc_main(const float* __restrict__ inputs, const float* __restrict__ states,
                         const float* __restrict__ gleak, const float* __restrict__ vleak,
                         const float* __restrict__ cmv,
                         const float* __restrict__ iw, const float* __restrict__ ib,
                         const float* __restrict__ ow, const float* __restrict__ ob,
                         const float4* __restrict__ Tm, const float4* __restrict__ Ts,
                         float* __restrict__ out)
{
  __shared__ float vsh[2][BT][Ssz];   // double-buffered state: 4 KB
  __shared__ float xsh[BT][Isz];      // 1 KB

  const int t = threadIdx.x;
  const int s = t & 127;
  const int r0 = (t >> 7) * R;        // rows this thread owns
  const int b0 = blockIdx.x * BT;

  // stage x = inputs*iw + ib and v = states into LDS
  { int r = t >> 6, i = t & 63;
    xsh[r][i] = inputs[(b0 + r) * Isz + i] * iw[i] + ib[i]; }
  for (int k = t; k < BT * Ssz; k += NT) {
    int r = k >> 7, ss = k & 127;
    vsh[0][r][ss] = states[(b0 + r) * Ssz + ss];
  }
  const float cmt = cmv[s] * 6.0f;    // cm / (1.0/6)
  const float gl = gleak[s];
  const float gv = gl * vleak[s];
  const float dbase = cmt + gl + 1e-8f;
  __syncthreads();

  // ---- sensory sums: full i-range (16 quads), this thread's R rows ----
  float sn[R] = {0.f, 0.f}, sd[R] = {0.f, 0.f};
  {
    const float4* pb = Ts + 1 * Ssz + s;       // points at b of quad 0
    #pragma unroll 2
    for (int q = 0; q < 16; ++q) {
      float4 a4 = pb[-Ssz], b4 = pb[0], w4 = pb[Ssz];
      pb += 3 * Ssz;
      #pragma unroll
      for (int r = 0; r < R; ++r) {
        float4 xq = *(const float4*)&xsh[r0 + r][q * 4];   // broadcast read
        #pragma unroll
        for (int jj = 0; jj < 4; ++jj) {
          float arg = fmaf((&a4.x)[jj], (&xq.x)[jj], (&b4.x)[jj]);
          float u = __builtin_amdgcn_exp2f(arg);
          float sig = __builtin_amdgcn_rcpf(1.0f + u);
          sn[r] = fmaf((&w4.x)[jj], sig, sn[r]);
          sd[r] = fmaf(fabsf((&w4.x)[jj]), sig, sd[r]);
        }
      }
    }
  }

  // ---- 6 ODE unfolds: full j-sum per thread, 1 barrier per unfold ----
  #pragma unroll 1
  for (int it = 0; it < 6; ++it) {
    const int cur = it & 1;
    const float* vcur = &vsh[cur][0][0];
    float num[R], den[R];
    #pragma unroll
    for (int r = 0; r < R; ++r) { num[r] = sn[r]; den[r] = sd[r]; }

    const float4* pb = Tm + 1 * Ssz + s;       // b of quad 0
    #pragma unroll 2
    for (int q = 0; q < 32; ++q) {
      float4 a4 = pb[-Ssz], b4 = pb[0], w4 = pb[Ssz];
      pb += 3 * Ssz;
      #pragma unroll
      for (int r = 0; r < R; ++r) {
        float4 vq = *(const float4*)&vcur[(r0 + r) * Ssz + q * 4];  // broadcast read
        #pragma unroll
        for (int jj = 0; jj < 4; ++jj) {
          float arg = fmaf((&a4.x)[jj], (&vq.x)[jj], (&b4.x)[jj]);
          float u = __builtin_amdgcn_exp2f(arg);
          float sig = __builtin_amdgcn_rcpf(1.0f + u);
          num[r] = fmaf((&w4.x)[jj], sig, num[r]);
          den[r] = fmaf(fabsf((&w4.x)[jj]), sig, den[r]);
        }
      }
    }

    #pragma unroll
    for (int r = 0; r < R; ++r) {
      float vo = vcur[(r0 + r) * Ssz + s];
      vsh[cur ^ 1][r0 + r][s] =
          (fmaf(cmt, vo, gv) + num[r]) * __builtin_amdgcn_rcpf(dbase + den[r]);
    }
    __syncthreads();   // new buffer fully written & visible before next unfold reads it
  }

  // final state lives in vsh[0] (6 flips: 0->1->0->1->0->1->0)
  // ---- outputs: [B*32] motor affine, then [B*128] v_pre ----
  for (int k = t; k < BT * Ssz; k += NT) {
    int r = k >> 7, ss = k & 127;
    out[Bsz * MOTOR + (b0 + r) * Ssz + ss] = vsh[0][r][ss];
  }
  if (t < BT * MOTOR) {
    int r = t >> 5, m = t & 31;
    out[(b0 + r) * MOTOR + m] = fmaf(vsh[0][r][m], ow[m], ob[m]);
  }
}

extern "C" void kernel_launch(void* const* d_in, const int* in_sizes, int n_in,
                              void* d_out, int out_size, void* d_ws, size_t ws_size,
                              hipStream_t stream) {
  const float* inputs = (const float*)d_in[0];
  const float* states = (const float*)d_in[1];
  const float* gleak  = (const float*)d_in[2];
  const float* vleak  = (const float*)d_in[3];
  const float* cmv    = (const float*)d_in[4];
  const float* w      = (const float*)d_in[5];
  const float* sigma  = (const float*)d_in[6];
  const float* mu     = (const float*)d_in[7];
  const float* erev   = (const float*)d_in[8];
  const float* sw     = (const float*)d_in[9];
  const float* ssig   = (const float*)d_in[10];
  const float* smu    = (const float*)d_in[11];
  const float* serev  = (const float*)d_in[12];
  const float* smask  = (const float*)d_in[13];
  const float* ssmask = (const float*)d_in[14];
  const float* iw     = (const float*)d_in[15];
  const float* ib     = (const float*)d_in[16];
  const float* ow     = (const float*)d_in[17];
  const float* ob     = (const float*)d_in[18];

  char* ws = (char*)d_ws;
  float4* Tm = (float4*)ws;                  // 32 quads * 3 * 128 * 16B = 196608
  float4* Ts = (float4*)(ws + 196608);       // 16 quads * 3 * 128 * 16B =  98304
  float* out = (float*)d_out;

  constexpr int prep_items = 32 * Ssz + 16 * Ssz;   // 6144
  ltc_prep<<<(prep_items + 255) / 256, 256, 0, stream>>>(
      w, sigma, mu, erev, smask, sw, ssig, smu, serev, ssmask, Tm, Ts);
  ltc_main<<<Bsz / BT, NT, 0, stream>>>(
      inputs, states, gleak, vleak, cmv, iw, ib, ow, ob, Tm, Ts, out);
}